// Round 12
// baseline (218.201 us; speedup 1.0000x reference)
//
#include <hip/hip_runtime.h>
#include <math.h>

#define BSZ 4
#define NN_ 192
#define DX 256
#define DE 64
#define DY 64
#define NH 8
#define NSQ (NN_*NN_)       // 36864
#define ROWS (BSZ*NN_)      // 768
#define EBLK 72
#define EROWS (NSQ/EBLK)    // 512

typedef __bf16 bf16;
typedef bf16 bf16x8 __attribute__((ext_vector_type(8)));
typedef bf16 bf16x4 __attribute__((ext_vector_type(4)));
typedef float f32x4 __attribute__((ext_vector_type(4)));

// ================= K1: front kernel (edge prerequisites only) =================
// blocks [0,144):   qkv MFMA GEMM, inline weight conversion
// blocks [144,336): W1a/W2a (A-frag, transposed) + W3 (B-frag) prep
// E-stats/X-stats/yx moved into the edge launch (no edge dependency) so they
// overlap edge's half-empty second block-round instead of serializing here.
__global__ __launch_bounds__(256) void front_kernel(
    const float* __restrict__ X,
    const float* __restrict__ qW, const float* __restrict__ qb,
    const float* __restrict__ kW, const float* __restrict__ kb,
    const float* __restrict__ vW, const float* __restrict__ vb,
    const float* __restrict__ emulW, const float* __restrict__ eaddW,
    const float* __restrict__ eoutW,
    float* __restrict__ Q, bf16* __restrict__ Kbf, float* __restrict__ V,
    bf16* __restrict__ W1a, bf16* __restrict__ W2a, bf16* __restrict__ W3)
{
    __shared__ __align__(16) char smemF[32768];
    int t = threadIdx.x;
    int blk = blockIdx.x;

    if (blk < 144) {
        // ---- qkv GEMM: M=64 rows (bm), N=64 cols of mat ----
        bf16* Wf = (bf16*)smemF;            // [ntl(4)][ks(8)][lane(64)][j(8)] = 16384 bf16
        int bm = blk / 12, bn = blk % 12;
        int mat = bn >> 2, n0 = (bn & 3) * 64;
        const float* Wsrc = (mat == 0) ? qW : (mat == 1) ? kW : vW;
        for (int it = 0; it < 16; ++it) {
            int k  = it*16 + (t >> 4);
            int nl = (t & 15) * 4;
            float4 wv = *(const float4*)&Wsrc[k*DX + n0 + nl];
            int ks = k >> 5, j = k & 7;
            int lb = ((k >> 3) & 3)*16 + (nl & 15);
            int ntl = nl >> 4;
            int base = ((ntl*8 + ks)*64);
            Wf[(base + lb+0)*8 + j] = (bf16)wv.x;
            Wf[(base + lb+1)*8 + j] = (bf16)wv.y;
            Wf[(base + lb+2)*8 + j] = (bf16)wv.z;
            Wf[(base + lb+3)*8 + j] = (bf16)wv.w;
        }
        __syncthreads();
        int l = t & 63, w = t >> 6;
        int c = l & 15, g = l >> 4;
        bf16x8 a[8];
        const float* Xrow = X + ((long)bm*64 + w*16 + c)*DX;
#pragma unroll
        for (int ks = 0; ks < 8; ++ks) {
            float4 x0 = *(const float4*)&Xrow[ks*32 + g*8];
            float4 x1 = *(const float4*)&Xrow[ks*32 + g*8 + 4];
            bf16x8 p;
            p[0]=(bf16)x0.x; p[1]=(bf16)x0.y; p[2]=(bf16)x0.z; p[3]=(bf16)x0.w;
            p[4]=(bf16)x1.x; p[5]=(bf16)x1.y; p[6]=(bf16)x1.z; p[7]=(bf16)x1.w;
            a[ks] = p;
        }
        f32x4 acc[4];
        f32x4 zero4 = {0.f,0.f,0.f,0.f};
#pragma unroll
        for (int ntl = 0; ntl < 4; ++ntl) acc[ntl] = zero4;
#pragma unroll
        for (int ntl = 0; ntl < 4; ++ntl)
#pragma unroll
            for (int ks = 0; ks < 8; ++ks) {
                bf16x8 bw = *(const bf16x8*)&Wf[((ntl*8 + ks)*64 + l)*8];
                acc[ntl] = __builtin_amdgcn_mfma_f32_16x16x32_bf16(a[ks], bw, acc[ntl], 0, 0, 0);
            }
#pragma unroll
        for (int ntl = 0; ntl < 4; ++ntl) {
            int coln = n0 + ntl*16 + c;
            long grow0 = (long)bm*64 + w*16 + g*4;
            if (mat == 0) {
                float bias = qb[coln];
#pragma unroll
                for (int reg = 0; reg < 4; ++reg)
                    Q[(grow0 + reg)*DX + coln] = acc[ntl][reg] + bias;
            } else if (mat == 1) {
                float bias = kb[coln];
#pragma unroll
                for (int reg = 0; reg < 4; ++reg)
                    Kbf[(grow0 + reg)*DX + coln] = (bf16)(acc[ntl][reg] + bias);
            } else {
                float bias = vb[coln];
#pragma unroll
                for (int reg = 0; reg < 4; ++reg)
                    V[(grow0 + reg)*DX + coln] = acc[ntl][reg] + bias;
            }
        }
    } else {
        int idx = (blk - 144)*256 + t;   // [0, 49152)
        if (idx < 32768) {
            // W1a/W2a: A-frag of W^T. f = ((head*2+mtn)*2+ks)*512 + l*8 + jj
            int f  = idx & 16383;
            int jj = f & 7;
            int l  = (f >> 3) & 63;
            int ks = (f >> 9) & 1;
            int mtn= (f >> 10) & 1;
            int hd = f >> 11;
            int de = ks*32 + (l >> 4)*8 + jj;
            int ncol = hd*32 + mtn*16 + (l & 15);
            if (idx < 16384) W1a[f] = (bf16)emulW[de*256 + ncol];
            else             W2a[f] = (bf16)eaddW[de*256 + ncol];
        } else {
            int f  = idx - 32768;
            int j  = f & 7;
            int l  = (f >> 3) & 63;
            int ks = (f >> 9) & 7;
            int nt = f >> 12;
            int k = ks*32 + (l>>4)*8 + j;
            int n = nt*16 + (l&15);
            W3[f] = (bf16)eoutW[k*64 + n];
        }
    }
}

// ================= K2: edge kernel (768 edge rows + 293 stats/yx blocks) =================
// blocks [0,768): round-4 edge body VERBATIM (best measured: 42.4us, VGPR 100).
// blocks [768,1056): E stats partials (512 threads, Y_s reused as 32KB scratch)
// blocks [1056,1060): X stats (t<256 active)
// block  1060:        yx1/yx2 (t<256 active)
// Theory: edge at 2 blocks/CU has a half-empty second round (256 blocks on 512
// slots) with HBM at 19% — the appended memory-bound stats blocks dispatch after
// the edge rows and fill that idle tail instead of serializing in front. Edge
// path code and launch_bounds untouched (11-round ledger: every edge-schedule
// intervention regressed). Post's inputs complete when this launch retires.
#define YS(row, colbyte) ((((row)<<9) + (colbyte)) ^ (((row)&7)<<4))
__global__ __launch_bounds__(512, 2) void edge_kernel(
    const float* __restrict__ E, const float* __restrict__ Q, const bf16* __restrict__ Kbf,
    const bf16* __restrict__ W1a, const bf16* __restrict__ W2a, const bf16* __restrict__ W3,
    const float* __restrict__ emulb, const float* __restrict__ eaddb,
    const float* __restrict__ eoutb,
    const float* __restrict__ X, const float* __restrict__ y,
    const float* __restrict__ yxaW, const float* __restrict__ yxab,
    const float* __restrict__ yxmW, const float* __restrict__ yxmb,
    float* __restrict__ newE, float* __restrict__ scores,
    float* __restrict__ epart, float* __restrict__ zx,
    float* __restrict__ yx1, float* __restrict__ yx2)
{
    __shared__ bf16 E_frag[4*2*64*8];              // 8KB  [jt(4)][ks(2)][lane(64)][8]
    __shared__ __align__(16) bf16 Y_s[64*256];     // 32KB, XOR-swizzled (stats: scratch)

    int t = threadIdx.x;
    int bid = blockIdx.x;

    if (bid >= ROWS) {
        // ================= stats / yx path (tail-fill blocks) =================
        int eb = bid - ROWS;
        if (eb < 288) {
            // E stats partials: 512 threads, 32 row-groups x 16 col-groups
            float* red = (float*)Y_s;              // [4][32][64] = 32KB
            int b = eb / EBLK, r0 = (eb % EBLK) * EROWS;
            int rg = t >> 4, cg = t & 15;
            const float* Eb = E + ((long)b*NSQ + r0)*DE + cg*4;
            float sm[4] = {0,0,0,0}, sq[4] = {0,0,0,0};
            float mn[4] = {1e30f,1e30f,1e30f,1e30f}, mx[4] = {-1e30f,-1e30f,-1e30f,-1e30f};
            for (int r = rg; r < EROWS; r += 32) {
                float4 v = *(const float4*)(Eb + (long)r*DE);
                float vv[4] = {v.x, v.y, v.z, v.w};
#pragma unroll
                for (int ci = 0; ci < 4; ++ci) {
                    sm[ci] += vv[ci]; sq[ci] += vv[ci]*vv[ci];
                    mn[ci] = fminf(mn[ci], vv[ci]); mx[ci] = fmaxf(mx[ci], vv[ci]);
                }
            }
#pragma unroll
            for (int ci = 0; ci < 4; ++ci) {
                red[(0*32 + rg)*64 + cg*4+ci] = sm[ci];
                red[(1*32 + rg)*64 + cg*4+ci] = sq[ci];
                red[(2*32 + rg)*64 + cg*4+ci] = mn[ci];
                red[(3*32 + rg)*64 + cg*4+ci] = mx[ci];
            }
            __syncthreads();
            if (t < 64) {
                float s = 0.f, q = 0.f, a = 1e30f, z = -1e30f;
                for (int r = 0; r < 32; ++r) {
                    s += red[(0*32 + r)*64 + t];
                    q += red[(1*32 + r)*64 + t];
                    a = fminf(a, red[(2*32 + r)*64 + t]);
                    z = fmaxf(z, red[(3*32 + r)*64 + t]);
                }
                float* ep = epart + (long)eb*256;
                ep[t] = s; ep[64+t] = q; ep[128+t] = a; ep[192+t] = z;
            }
        } else if (eb < 292) {
            // X stats (one block per batch; t<256 = one column each)
            if (t < 256) {
                int b = eb - 288;
                const float* Xb = X + (long)b*NN_*DX;
                float sm = 0.f, sq = 0.f, mn = 1e30f, mx = -1e30f;
                for (int n = 0; n < NN_; ++n) {
                    float v = Xb[(long)n*DX + t];
                    sm += v; sq += v*v; mn = fminf(mn, v); mx = fmaxf(mx, v);
                }
                float mean = sm / (float)NN_;
                float sd = sqrtf(fmaxf(0.f, (sq - sm*sm/(float)NN_) / (float)(NN_-1)));
                float* zb = zx + b*4*DX;
                zb[t] = mean; zb[DX+t] = mn; zb[2*DX+t] = mx; zb[3*DX+t] = sd;
            }
        } else {
            // yx1/yx2
            if (t < 256) {
                for (int bb = 0; bb < BSZ; ++bb) {
                    float a1 = yxab[t], a2 = yxmb[t];
                    for (int k = 0; k < DY; ++k) {
                        float yv = y[bb*DY + k];
                        a1 += yv * yxaW[k*DX + t];
                        a2 += yv * yxmW[k*DX + t];
                    }
                    yx1[bb*DX + t] = a1;
                    yx2[bb*DX + t] = a2;
                }
            }
        }
        return;
    }

    // ================= edge row path (round-4 body, verbatim) =================
    int b = bid / NN_;
    int i = bid % NN_;

    int l = t & 63, w = t >> 6;
    int c = l & 15, g = l >> 4;
    char* Yb = (char*)Y_s;

    // staging geometry (j0-independent part)
    int row = t >> 3, k8 = (t & 7) * 8;
    const float* Erow = E + ((long)b*NSQ + (long)i*NN_ + row)*DE + k8;
    int mt = row >> 4, cc = row & 15, kss = k8 >> 5, gg = (k8 >> 3) & 3;
    int fidx = (((mt*2 + kss)*64) + gg*16 + cc)*8;

    // per-lane constants for head w: ncol = w*32 + mtn*16 + g*4 + reg
    const float scale = 0.17677669529663687f;   // 1/sqrt(32)
    int colbase = w*32 + g*4;
    const float* Qp = Q + ((long)b*NN_ + i)*DX + colbase;
    float4 q0 = *(const float4*)&Qp[0];
    float4 q1 = *(const float4*)&Qp[16];
    float4 m0 = *(const float4*)&emulb[colbase];
    float4 m1 = *(const float4*)&emulb[colbase + 16];
    float4 a0 = *(const float4*)&eaddb[colbase];
    float4 a1 = *(const float4*)&eaddb[colbase + 16];
    float qs[2][4] = {{q0.x*scale, q0.y*scale, q0.z*scale, q0.w*scale},
                      {q1.x*scale, q1.y*scale, q1.z*scale, q1.w*scale}};
    float b1[2][4] = {{m0.x+1.f, m0.y+1.f, m0.z+1.f, m0.w+1.f},
                      {m1.x+1.f, m1.y+1.f, m1.z+1.f, m1.w+1.f}};
    float b2[2][4] = {{a0.x, a0.y, a0.z, a0.w},
                      {a1.x, a1.y, a1.z, a1.w}};

    // W^T A-frags for head w (loaded once for all 3 tiles)
    bf16x8 wa1[2][2], wa2[2][2];
#pragma unroll
    for (int mtn = 0; mtn < 2; ++mtn)
#pragma unroll
        for (int ks = 0; ks < 2; ++ks) {
            wa1[mtn][ks] = *(const bf16x8*)&W1a[(((w*2 + mtn)*2 + ks)*64 + l)*8];
            wa2[mtn][ks] = *(const bf16x8*)&W2a[(((w*2 + mtn)*2 + ks)*64 + l)*8];
        }

    f32x4 zero4 = {0.f, 0.f, 0.f, 0.f};
    long srow0 = ((long)(b*NH + w)*NN_ + i)*NN_;
    const bf16* Krow0 = Kbf + (long)b*NN_*DX + colbase;
    long ebase = (long)b*NSQ + (long)i*NN_;
    int mt3 = w >> 1, n0_ = (w & 1) * 2;

#pragma unroll 1
    for (int tile = 0; tile < 3; ++tile) {
        int j0 = tile * 64;

        // ---- stage E tile -> bf16 frag layout ----
        {
            const float* Ep = Erow + (long)j0*DE;
            float4 f0 = ((const float4*)Ep)[0];
            float4 f1 = ((const float4*)Ep)[1];
            bf16x8 p;
            p[0]=(bf16)f0.x; p[1]=(bf16)f0.y; p[2]=(bf16)f0.z; p[3]=(bf16)f0.w;
            p[4]=(bf16)f1.x; p[5]=(bf16)f1.y; p[6]=(bf16)f1.z; p[7]=(bf16)f1.w;
            *(bf16x8*)&E_frag[fidx] = p;
        }
        __syncthreads();   // E_frag ready; also guarantees prev GEMM3 Y_s reads done

        // ---- GEMM1-T + elementwise ----
#pragma unroll
        for (int ntj = 0; ntj < 4; ++ntj) {
            f32x4 acc1[2] = {zero4, zero4};
            f32x4 acc2[2] = {zero4, zero4};
            bf16x8 eb0 = *(const bf16x8*)&E_frag[((ntj*2 + 0)*64 + l)*8];
            bf16x8 eb1 = *(const bf16x8*)&E_frag[((ntj*2 + 1)*64 + l)*8];
#pragma unroll
            for (int mtn = 0; mtn < 2; ++mtn) {
                acc1[mtn] = __builtin_amdgcn_mfma_f32_16x16x32_bf16(wa1[mtn][0], eb0, acc1[mtn], 0, 0, 0);
                acc2[mtn] = __builtin_amdgcn_mfma_f32_16x16x32_bf16(wa2[mtn][0], eb0, acc2[mtn], 0, 0, 0);
                acc1[mtn] = __builtin_amdgcn_mfma_f32_16x16x32_bf16(wa1[mtn][1], eb1, acc1[mtn], 0, 0, 0);
                acc2[mtn] = __builtin_amdgcn_mfma_f32_16x16x32_bf16(wa2[mtn][1], eb1, acc2[mtn], 0, 0, 0);
            }
            // lane owns edge j = ntj*16 + c, ncols colbase..+3 and colbase+16..+19
            int j = ntj*16 + c;
            const bf16* Kp = Krow0 + (long)(j0 + j)*DX;
            bf16x4 kv0 = *(const bf16x4*)&Kp[0];
            bf16x4 kv1 = *(const bf16x4*)&Kp[16];
            float sc = 0.f;
            bf16x4 y0, y1;
#pragma unroll
            for (int reg = 0; reg < 4; ++reg) {
                float kva = (float)kv0[reg];
                float kvb = (float)kv1[reg];
                float ya = qs[0][reg]*kva*(acc1[0][reg] + b1[0][reg]) + acc2[0][reg] + b2[0][reg];
                float yb = qs[1][reg]*kvb*(acc1[1][reg] + b1[1][reg]) + acc2[1][reg] + b2[1][reg];
                sc += ya + yb;
                y0[reg] = (bf16)ya;
                y1[reg] = (bf16)yb;
            }
            *(bf16x4*)(Yb + YS(j, (colbase<<1)))      = y0;
            *(bf16x4*)(Yb + YS(j, (colbase<<1) + 32)) = y1;
            sc += __shfl_xor(sc, 16);
            sc += __shfl_xor(sc, 32);
            if (g == 0) scores[srow0 + j0 + j] = sc;
        }
        __syncthreads();   // Y_s ready

        // ---- GEMM3: newE = Y @ eoutW + eoutb ----
        f32x4 acc3[2];
        acc3[0] = zero4; acc3[1] = zero4;
#pragma unroll
        for (int ks = 0; ks < 8; ++ks) {
            bf16x8 a = *(const bf16x8*)(Yb + YS(mt3*16 + c, ks*64 + g*16));
#pragma unroll
            for (int nn = 0; nn < 2; ++nn) {
                bf16x8 bw = *(const bf16x8*)&W3[(((n0_+nn)*8 + ks)*64 + l)*8];
                acc3[nn] = __builtin_amdgcn_mfma_f32_16x16x32_bf16(a, bw, acc3[nn], 0, 0, 0);
            }
        }
        long eb_ = ebase + j0;
#pragma unroll
        for (int nn = 0; nn < 2; ++nn) {
            int o = (n0_+nn)*16 + c;
            float bias = eoutb[o];
#pragma unroll
            for (int reg = 0; reg < 4; ++reg)
                newE[(eb_ + mt3*16 + g*4 + reg)*DE + o] = acc3[nn][reg] + bias;
        }
    }
}

// ================= K3: post kernel =================
// blocks [0,384): attn (2 rows/block); blocks [384,388): ypath
__global__ __launch_bounds__(256) void post_kernel(
    const float* __restrict__ scores, const float* __restrict__ V,
    const float* __restrict__ yx1, const float* __restrict__ yx2,
    const float* __restrict__ xoutW, const float* __restrict__ xoutb,
    const float* __restrict__ epart, const float* __restrict__ zx,
    const float* __restrict__ y,
    const float* __restrict__ xyW, const float* __restrict__ xyb,
    const float* __restrict__ eyW, const float* __restrict__ eyb,
    const float* __restrict__ y1W, const float* __restrict__ y1b,
    const float* __restrict__ y2W, const float* __restrict__ y2b,
    float* __restrict__ newX, float* __restrict__ outy)
{
    __shared__ __align__(16) char smemP[15360];
    int t = threadIdx.x;
    int blk = blockIdx.x;

    if (blk < 384) {
        float* s2 = (float*)smemP;            // [2][8][200]
        float* t2 = s2 + 3200;                // [2][256]
        int b = blk / 96;
        int i0 = (blk % 96) * 2;

        for (int idx = t; idx < 2*NH*NN_; idx += 256) {
            int rr = idx / (NH*NN_);
            int rem = idx - rr*(NH*NN_);
            int h = rem / NN_, j = rem - h*NN_;
            s2[(rr*NH + h)*200 + j] = scores[(((long)(b*NH + h))*NN_ + (i0+rr))*NN_ + j];
        }
        __syncthreads();
        {
            int w = t >> 6, l64 = t & 63;
            int rr = w >> 1;
#pragma unroll
            for (int hh = 0; hh < 4; ++hh) {
                int h = (w & 1)*4 + hh;
                float* srw = &s2[(rr*NH + h)*200];
                float v0 = srw[l64], v1 = srw[l64+64], v2 = srw[l64+128];
                float m = fmaxf(fmaxf(v0, v1), v2);
                m = fmaxf(m, __shfl_xor(m, 1));  m = fmaxf(m, __shfl_xor(m, 2));
                m = fmaxf(m, __shfl_xor(m, 4));  m = fmaxf(m, __shfl_xor(m, 8));
                m = fmaxf(m, __shfl_xor(m, 16)); m = fmaxf(m, __shfl_xor(m, 32));
                v0 = __expf(v0 - m); v1 = __expf(v1 - m); v2 = __expf(v2 - m);
                float sum = v0 + v1 + v2;
                sum += __shfl_xor(sum, 1);  sum += __shfl_xor(sum, 2);
                sum += __shfl_xor(sum, 4);  sum += __shfl_xor(sum, 8);
                sum += __shfl_xor(sum, 16); sum += __shfl_xor(sum, 32);
                float inv = 1.0f / sum;
                srw[l64] = v0*inv; srw[l64+64] = v1*inv; srw[l64+128] = v2*inv;
            }
        }
        __syncthreads();

        float a0 = 0.f, a1 = 0.f;
        int hd = t >> 5;
        const float* s0r = &s2[(0*NH + hd)*200];
        const float* s1r = &s2[(1*NH + hd)*200];
        const float* Vb = V + (long)b*NN_*DX + t;
        for (int j = 0; j < NN_; j += 4) {
            float vv0 = Vb[(long)(j+0)*DX];
            float vv1 = Vb[(long)(j+1)*DX];
            float vv2 = Vb[(long)(j+2)*DX];
            float vv3 = Vb[(long)(j+3)*DX];
            a0 += s0r[j]*vv0 + s0r[j+1]*vv1 + s0r[j+2]*vv2 + s0r[j+3]*vv3;
            a1 += s1r[j]*vv0 + s1r[j+1]*vv1 + s1r[j+2]*vv2 + s1r[j+3]*vv3;
        }
        float y1v = yx1[b*DX + t], y2v = yx2[b*DX + t] + 1.0f;
        t2[t] = y1v + y2v * a0;
        t2[256 + t] = y1v + y2v * a1;
        __syncthreads();

        float ax0 = xoutb[t], ax1 = ax0;
        for (int k = 0; k < DX; k += 4) {
            float w0 = xoutW[(k+0)*DX+t], w1 = xoutW[(k+1)*DX+t];
            float w2 = xoutW[(k+2)*DX+t], w3 = xoutW[(k+3)*DX+t];
            float4 x0 = *(const float4*)&t2[k];
            float4 x1 = *(const float4*)&t2[256 + k];
            ax0 += x0.x*w0 + x0.y*w1 + x0.z*w2 + x0.w*w3;
            ax1 += x1.x*w0 + x1.y*w1 + x1.z*w2 + x1.w*w3;
        }
        newX[((long)(b*NN_ + i0    ))*DX + t] = ax0;
        newX[((long)(b*NN_ + i0 + 1))*DX + t] = ax1;
    } else {
        float* pe   = (float*)smemP;    // [4][4][64]
        float* ze_s = pe + 1024;        // 256
        float* zx_s = ze_s + 256;       // 1024
        float* redx = zx_s + 1024;      // [4][64]
        float* rede = redx + 256;       // 256
        float* v_s  = rede + 256;       // 64
        float* h_s  = v_s + 64;         // 64
        int b = blk - 384;
        int o = t & 63, q = t >> 6;

        {
            float sm = 0.f, sq = 0.f, mn = 1e30f, mx = -1e30f;
            const float* ep = epart + (long)b*EBLK*256;
            for (int bb = q; bb < EBLK; bb += 4) {
                sm += ep[bb*256 + o];
                sq += ep[bb*256 + 64 + o];
                mn = fminf(mn, ep[bb*256 + 128 + o]);
                mx = fmaxf(mx, ep[bb*256 + 192 + o]);
            }
            pe[(0*4 + q)*64 + o] = sm; pe[(1*4 + q)*64 + o] = sq;
            pe[(2*4 + q)*64 + o] = mn; pe[(3*4 + q)*64 + o] = mx;
        }
        for (int cidx = t; cidx < 1024; cidx += 256) zx_s[cidx] = zx[b*1024 + cidx];
        __syncthreads();
        if (t < 64) {
            float s  = pe[t] + pe[64+t] + pe[128+t] + pe[192+t];
            float qq = pe[256+t] + pe[320+t] + pe[384+t] + pe[448+t];
            float a  = fminf(fminf(pe[512+t], pe[576+t]), fminf(pe[640+t], pe[704+t]));
            float z  = fmaxf(fmaxf(pe[768+t], pe[832+t]), fmaxf(pe[896+t], pe[960+t]));
            float cnt = (float)NSQ;
            float mean = s / cnt;
            float sd = sqrtf(fmaxf(0.f, (qq - s*s/cnt) / (cnt - 1.f)));
            ze_s[t] = mean; ze_s[64+t] = a; ze_s[128+t] = z; ze_s[192+t] = sd;
        }
        __syncthreads();

        float xa = 0.f;
        for (int k = q*256; k < q*256 + 256; ++k) xa += zx_s[k] * xyW[k*DY + o];
        float ea = 0.f;
        for (int k = q*64; k < q*64 + 64; ++k) ea += ze_s[k] * eyW[k*DY + o];
        redx[q*64 + o] = xa; rede[q*64 + o] = ea;
        __syncthreads();
        if (t < 64) {
            float a = xyb[t] + redx[t] + redx[64+t] + redx[128+t] + redx[192+t];
            float e = eyb[t] + rede[t] + rede[64+t] + rede[128+t] + rede[192+t];
            v_s[t] = y[b*DY + t] + a + e;
        }
        __syncthreads();

        float hv = 0.f;
        for (int k = q*16; k < q*16 + 16; ++k) hv += v_s[k] * y1W[k*DY + o];
        redx[q*64 + o] = hv;
        __syncthreads();
        if (t < 64)
            h_s[t] = fmaxf(y1b[t] + redx[t] + redx[64+t] + redx[128+t] + redx[192+t], 0.f);
        __syncthreads();

        float ov = 0.f;
        for (int k = q*16; k < q*16 + 16; ++k) ov += h_s[k] * y2W[k*DY + o];
        redx[q*64 + o] = ov;
        __syncthreads();
        if (t < 64)
            outy[b*DY + t] = y2b[t] + redx[t] + redx[64+t] + redx[128+t] + redx[192+t];
    }
}

// ---------------- launch ----------------
extern "C" void kernel_launch(void* const* d_in, const int* in_sizes, int n_in,
                              void* d_out, int out_size, void* d_ws, size_t ws_size,
                              hipStream_t stream) {
    const float* X     = (const float*)d_in[0];
    const float* E     = (const float*)d_in[1];
    const float* y     = (const float*)d_in[2];
    const float* qW    = (const float*)d_in[4];
    const float* qb    = (const float*)d_in[5];
    const float* kW    = (const float*)d_in[6];
    const float* kb    = (const float*)d_in[7];
    const float* vW    = (const float*)d_in[8];
    const float* vb    = (const float*)d_in[9];
    const float* emulW = (const float*)d_in[10];
    const float* emulb = (const float*)d_in[11];
    const float* eaddW = (const float*)d_in[12];
    const float* eaddb = (const float*)d_in[13];
    const float* yxmW  = (const float*)d_in[14];
    const float* yxmb  = (const float*)d_in[15];
    const float* yxaW  = (const float*)d_in[16];
    const float* yxab  = (const float*)d_in[17];
    const float* xoutW = (const float*)d_in[18];
    const float* xoutb = (const float*)d_in[19];
    const float* eoutW = (const float*)d_in[20];
    const float* eoutb = (const float*)d_in[21];
    const float* xyW   = (const float*)d_in[22];
    const float* xyb   = (const float*)d_in[23];
    const float* eyW   = (const float*)d_in[24];
    const float* eyb   = (const float*)d_in[25];
    const float* y1W   = (const float*)d_in[26];
    const float* y1b   = (const float*)d_in[27];
    const float* y2W   = (const float*)d_in[28];
    const float* y2b   = (const float*)d_in[29];

    float* out  = (float*)d_out;
    float* newX = out;
    float* newE = out + (long)ROWS*DX;
    float* outy = out + (long)ROWS*DX + (long)BSZ*NSQ*DE;

    float* ws   = (float*)d_ws;
    float* Q    = ws;                          // 196608 f
    float* V    = Q + (long)ROWS*DX;           // 196608 f
    float* yx1  = V + (long)ROWS*DX;           // 1024 f
    float* yx2  = yx1 + BSZ*DX;                // 1024 f
    float* scr  = yx2 + BSZ*DX;                // 1179648 f  [b][h][i][j]
    float* ep   = scr + (long)BSZ*NH*NSQ;      // 73728 f
    float* zx   = ep + (long)BSZ*EBLK*256;     // 4096 f
    bf16*  Kbf  = (bf16*)(zx + BSZ*4*DX);      // 196608 bf16
    bf16*  W1a  = Kbf + (long)ROWS*DX;         // 16384 bf16
    bf16*  W2a  = W1a + 16384;                 // 16384 bf16
    bf16*  W3   = W2a + 16384;                 // 16384 bf16

    front_kernel<<<336, 256, 0, stream>>>(X, qW, qb, kW, kb, vW, vb,
                                          emulW, eaddW, eoutW,
                                          Q, Kbf, V, W1a, W2a, W3);
    edge_kernel<<<ROWS + 288 + 4 + 1, 512, 0, stream>>>(
                                          E, Q, Kbf, W1a, W2a, W3,
                                          emulb, eaddb, eoutb,
                                          X, y, yxaW, yxab, yxmW, yxmb,
                                          newE, scr, ep, zx, yx1, yx2);
    post_kernel<<<388, 256, 0, stream>>>(scr, V, yx1, yx2, xoutW, xoutb,
                                         ep, zx, y, xyW, xyb, eyW, eyb,
                                         y1W, y1b, y2W, y2b, newX, outy);
}

// Round 14
// 211.591 us; speedup vs baseline: 1.0312x; 1.0312x over previous
//
#include <hip/hip_runtime.h>
#include <math.h>

#define BSZ 4
#define NN_ 192
#define DX 256
#define DE 64
#define DY 64
#define NH 8
#define NSQ (NN_*NN_)       // 36864
#define ROWS (BSZ*NN_)      // 768
#define EBLK 72
#define EROWS (NSQ/EBLK)    // 512

typedef __bf16 bf16;
typedef bf16 bf16x8 __attribute__((ext_vector_type(8)));
typedef bf16 bf16x4 __attribute__((ext_vector_type(4)));
typedef float f32x4 __attribute__((ext_vector_type(4)));

// ================= K1: front kernel =================
// blocks [0,144):   qkv MFMA GEMM, inline weight conversion
// block  144:       yx1/yx2
// blocks [145,433): E stats partials (288)
// blocks [433,437): X stats (4)
// blocks [437,629): W1a/W2a (A-frag, transposed) + W3 (B-frag) prep (192)
__global__ __launch_bounds__(256) void front_kernel(
    const float* __restrict__ X, const float* __restrict__ E, const float* __restrict__ y,
    const float* __restrict__ qW, const float* __restrict__ qb,
    const float* __restrict__ kW, const float* __restrict__ kb,
    const float* __restrict__ vW, const float* __restrict__ vb,
    const float* __restrict__ emulW, const float* __restrict__ eaddW,
    const float* __restrict__ eoutW,
    const float* __restrict__ yxaW, const float* __restrict__ yxab,
    const float* __restrict__ yxmW, const float* __restrict__ yxmb,
    float* __restrict__ Q, bf16* __restrict__ Kbf, float* __restrict__ V,
    float* __restrict__ yx1, float* __restrict__ yx2,
    float* __restrict__ epart, float* __restrict__ zx,
    bf16* __restrict__ W1a, bf16* __restrict__ W2a, bf16* __restrict__ W3)
{
    __shared__ __align__(16) char smemF[32768];
    int t = threadIdx.x;
    int blk = blockIdx.x;

    if (blk < 144) {
        // ---- qkv GEMM: M=64 rows (bm), N=64 cols of mat ----
        bf16* Wf = (bf16*)smemF;            // [ntl(4)][ks(8)][lane(64)][j(8)] = 16384 bf16
        int bm = blk / 12, bn = blk % 12;
        int mat = bn >> 2, n0 = (bn & 3) * 64;
        const float* Wsrc = (mat == 0) ? qW : (mat == 1) ? kW : vW;
        for (int it = 0; it < 16; ++it) {
            int k  = it*16 + (t >> 4);
            int nl = (t & 15) * 4;
            float4 wv = *(const float4*)&Wsrc[k*DX + n0 + nl];
            int ks = k >> 5, j = k & 7;
            int lb = ((k >> 3) & 3)*16 + (nl & 15);
            int ntl = nl >> 4;
            int base = ((ntl*8 + ks)*64);
            Wf[(base + lb+0)*8 + j] = (bf16)wv.x;
            Wf[(base + lb+1)*8 + j] = (bf16)wv.y;
            Wf[(base + lb+2)*8 + j] = (bf16)wv.z;
            Wf[(base + lb+3)*8 + j] = (bf16)wv.w;
        }
        __syncthreads();
        int l = t & 63, w = t >> 6;
        int c = l & 15, g = l >> 4;
        bf16x8 a[8];
        const float* Xrow = X + ((long)bm*64 + w*16 + c)*DX;
#pragma unroll
        for (int ks = 0; ks < 8; ++ks) {
            float4 x0 = *(const float4*)&Xrow[ks*32 + g*8];
            float4 x1 = *(const float4*)&Xrow[ks*32 + g*8 + 4];
            bf16x8 p;
            p[0]=(bf16)x0.x; p[1]=(bf16)x0.y; p[2]=(bf16)x0.z; p[3]=(bf16)x0.w;
            p[4]=(bf16)x1.x; p[5]=(bf16)x1.y; p[6]=(bf16)x1.z; p[7]=(bf16)x1.w;
            a[ks] = p;
        }
        f32x4 acc[4];
        f32x4 zero4 = {0.f,0.f,0.f,0.f};
#pragma unroll
        for (int ntl = 0; ntl < 4; ++ntl) acc[ntl] = zero4;
#pragma unroll
        for (int ntl = 0; ntl < 4; ++ntl)
#pragma unroll
            for (int ks = 0; ks < 8; ++ks) {
                bf16x8 bw = *(const bf16x8*)&Wf[((ntl*8 + ks)*64 + l)*8];
                acc[ntl] = __builtin_amdgcn_mfma_f32_16x16x32_bf16(a[ks], bw, acc[ntl], 0, 0, 0);
            }
#pragma unroll
        for (int ntl = 0; ntl < 4; ++ntl) {
            int coln = n0 + ntl*16 + c;
            long grow0 = (long)bm*64 + w*16 + g*4;
            if (mat == 0) {
                float bias = qb[coln];
#pragma unroll
                for (int reg = 0; reg < 4; ++reg)
                    Q[(grow0 + reg)*DX + coln] = acc[ntl][reg] + bias;
            } else if (mat == 1) {
                float bias = kb[coln];
#pragma unroll
                for (int reg = 0; reg < 4; ++reg)
                    Kbf[(grow0 + reg)*DX + coln] = (bf16)(acc[ntl][reg] + bias);
            } else {
                float bias = vb[coln];
#pragma unroll
                for (int reg = 0; reg < 4; ++reg)
                    V[(grow0 + reg)*DX + coln] = acc[ntl][reg] + bias;
            }
        }
    } else if (blk == 144) {
        for (int bb = 0; bb < BSZ; ++bb) {
            float a1 = yxab[t], a2 = yxmb[t];
            for (int k = 0; k < DY; ++k) {
                float yv = y[bb*DY + k];
                a1 += yv * yxaW[k*DX + t];
                a2 += yv * yxmW[k*DX + t];
            }
            yx1[bb*DX + t] = a1;
            yx2[bb*DX + t] = a2;
        }
    } else if (blk < 433) {
        int eb = blk - 145;
        int b = eb / EBLK, r0 = (eb % EBLK) * EROWS;
        int rg = t >> 4, cg = t & 15;
        const float* Eb = E + ((long)b*NSQ + r0)*DE + cg*4;
        float sm[4] = {0,0,0,0}, sq[4] = {0,0,0,0};
        float mn[4] = {1e30f,1e30f,1e30f,1e30f}, mx[4] = {-1e30f,-1e30f,-1e30f,-1e30f};
        for (int r = rg; r < EROWS; r += 16) {
            float4 v = *(const float4*)(Eb + (long)r*DE);
            float vv[4] = {v.x, v.y, v.z, v.w};
#pragma unroll
            for (int ci = 0; ci < 4; ++ci) {
                sm[ci] += vv[ci]; sq[ci] += vv[ci]*vv[ci];
                mn[ci] = fminf(mn[ci], vv[ci]); mx[ci] = fmaxf(mx[ci], vv[ci]);
            }
        }
        float (*red)[16][64] = (float (*)[16][64])smemF;
#pragma unroll
        for (int ci = 0; ci < 4; ++ci) {
            red[0][rg][cg*4+ci] = sm[ci]; red[1][rg][cg*4+ci] = sq[ci];
            red[2][rg][cg*4+ci] = mn[ci]; red[3][rg][cg*4+ci] = mx[ci];
        }
        __syncthreads();
        if (t < 64) {
            float s = 0.f, q = 0.f, a = 1e30f, z = -1e30f;
            for (int r = 0; r < 16; ++r) {
                s += red[0][r][t]; q += red[1][r][t];
                a = fminf(a, red[2][r][t]); z = fmaxf(z, red[3][r][t]);
            }
            float* ep = epart + (long)eb*256;
            ep[t] = s; ep[64+t] = q; ep[128+t] = a; ep[192+t] = z;
        }
    } else if (blk < 437) {
        int b = blk - 433;
        const float* Xb = X + (long)b*NN_*DX;
        float sm = 0.f, sq = 0.f, mn = 1e30f, mx = -1e30f;
        for (int n = 0; n < NN_; ++n) {
            float v = Xb[(long)n*DX + t];
            sm += v; sq += v*v; mn = fminf(mn, v); mx = fmaxf(mx, v);
        }
        float mean = sm / (float)NN_;
        float sd = sqrtf(fmaxf(0.f, (sq - sm*sm/(float)NN_) / (float)(NN_-1)));
        float* zb = zx + b*4*DX;
        zb[t] = mean; zb[DX+t] = mn; zb[2*DX+t] = mx; zb[3*DX+t] = sd;
    } else {
        int idx = (blk - 437)*256 + t;   // [0, 49152)
        if (idx < 32768) {
            // W1a/W2a: A-frag of W^T. f = ((head*2+mtn)*2+ks)*512 + l*8 + jj
            int f  = idx & 16383;
            int jj = f & 7;
            int l  = (f >> 3) & 63;
            int ks = (f >> 9) & 1;
            int mtn= (f >> 10) & 1;
            int hd = f >> 11;
            int de = ks*32 + (l >> 4)*8 + jj;
            int ncol = hd*32 + mtn*16 + (l & 15);
            if (idx < 16384) W1a[f] = (bf16)emulW[de*256 + ncol];
            else             W2a[f] = (bf16)eaddW[de*256 + ncol];
        } else {
            int f  = idx - 32768;
            int j  = f & 7;
            int l  = (f >> 3) & 63;
            int ks = (f >> 9) & 7;
            int nt = f >> 12;
            int k = ks*32 + (l>>4)*8 + j;
            int n = nt*16 + (l&15);
            W3[f] = (bf16)eoutW[k*64 + n];
        }
    }
}

// ================= K2: edge kernel (768 blocks = one full row i each) =================
// FINAL: round-4 configuration — session best, verified r4/r11 (total 212.3us,
// edge 42.4us, VGPR 100, no spill). GRID MUST BE BSZ*NN_ = 768 (r13's core dump
// was a 2304-block launch of this 768-block body: b=bid/192 ran to 11, OOB).
// Twelve-round ledger: occupancy lift (r2) null; staging traffic cut (r3) null;
// fixed-cost amortization (this shell, r4) +2; post-fusion (r5) -21; explicit
// prefetch under tight bounds (r1/r7) spills, under free bounds (r8) null;
// LDS-only barriers (r9) -12; stats tail-fill (r12) -6. Latency-structure-bound
// at all-pipes<25%; manual scheduling interventions measured as losses in both
// directions. Hold.
#define YS(row, colbyte) ((((row)<<9) + (colbyte)) ^ (((row)&7)<<4))
__global__ __launch_bounds__(512, 2) void edge_kernel(
    const float* __restrict__ E, const float* __restrict__ Q, const bf16* __restrict__ Kbf,
    const bf16* __restrict__ W1a, const bf16* __restrict__ W2a, const bf16* __restrict__ W3,
    const float* __restrict__ emulb, const float* __restrict__ eaddb,
    const float* __restrict__ eoutb,
    float* __restrict__ newE, float* __restrict__ scores)
{
    __shared__ bf16 E_frag[4*2*64*8];              // 8KB  [jt(4)][ks(2)][lane(64)][8]
    __shared__ __align__(16) bf16 Y_s[64*256];     // 32KB, XOR-swizzled

    int t = threadIdx.x;
    int bid = blockIdx.x;
    int b = bid / NN_;
    int i = bid % NN_;

    int l = t & 63, w = t >> 6;
    int c = l & 15, g = l >> 4;
    char* Yb = (char*)Y_s;

    // staging geometry (j0-independent part)
    int row = t >> 3, k8 = (t & 7) * 8;
    const float* Erow = E + ((long)b*NSQ + (long)i*NN_ + row)*DE + k8;
    int mt = row >> 4, cc = row & 15, kss = k8 >> 5, gg = (k8 >> 3) & 3;
    int fidx = (((mt*2 + kss)*64) + gg*16 + cc)*8;

    // per-lane constants for head w: ncol = w*32 + mtn*16 + g*4 + reg
    const float scale = 0.17677669529663687f;   // 1/sqrt(32)
    int colbase = w*32 + g*4;
    const float* Qp = Q + ((long)b*NN_ + i)*DX + colbase;
    float4 q0 = *(const float4*)&Qp[0];
    float4 q1 = *(const float4*)&Qp[16];
    float4 m0 = *(const float4*)&emulb[colbase];
    float4 m1 = *(const float4*)&emulb[colbase + 16];
    float4 a0 = *(const float4*)&eaddb[colbase];
    float4 a1 = *(const float4*)&eaddb[colbase + 16];
    float qs[2][4] = {{q0.x*scale, q0.y*scale, q0.z*scale, q0.w*scale},
                      {q1.x*scale, q1.y*scale, q1.z*scale, q1.w*scale}};
    float b1[2][4] = {{m0.x+1.f, m0.y+1.f, m0.z+1.f, m0.w+1.f},
                      {m1.x+1.f, m1.y+1.f, m1.z+1.f, m1.w+1.f}};
    float b2[2][4] = {{a0.x, a0.y, a0.z, a0.w},
                      {a1.x, a1.y, a1.z, a1.w}};

    // W^T A-frags for head w (loaded once for all 3 tiles)
    bf16x8 wa1[2][2], wa2[2][2];
#pragma unroll
    for (int mtn = 0; mtn < 2; ++mtn)
#pragma unroll
        for (int ks = 0; ks < 2; ++ks) {
            wa1[mtn][ks] = *(const bf16x8*)&W1a[(((w*2 + mtn)*2 + ks)*64 + l)*8];
            wa2[mtn][ks] = *(const bf16x8*)&W2a[(((w*2 + mtn)*2 + ks)*64 + l)*8];
        }

    f32x4 zero4 = {0.f, 0.f, 0.f, 0.f};
    long srow0 = ((long)(b*NH + w)*NN_ + i)*NN_;
    const bf16* Krow0 = Kbf + (long)b*NN_*DX + colbase;
    long ebase = (long)b*NSQ + (long)i*NN_;
    int mt3 = w >> 1, n0_ = (w & 1) * 2;

#pragma unroll 1
    for (int tile = 0; tile < 3; ++tile) {
        int j0 = tile * 64;

        // ---- stage E tile -> bf16 frag layout ----
        // E_frag is free here: its last readers (GEMM1 of the previous tile)
        // all passed the previous Y_s-ready barrier.
        {
            const float* Ep = Erow + (long)j0*DE;
            float4 f0 = ((const float4*)Ep)[0];
            float4 f1 = ((const float4*)Ep)[1];
            bf16x8 p;
            p[0]=(bf16)f0.x; p[1]=(bf16)f0.y; p[2]=(bf16)f0.z; p[3]=(bf16)f0.w;
            p[4]=(bf16)f1.x; p[5]=(bf16)f1.y; p[6]=(bf16)f1.z; p[7]=(bf16)f1.w;
            *(bf16x8*)&E_frag[fidx] = p;
        }
        __syncthreads();   // E_frag ready; also guarantees prev GEMM3 Y_s reads done

        // ---- GEMM1-T + elementwise ----
#pragma unroll
        for (int ntj = 0; ntj < 4; ++ntj) {
            f32x4 acc1[2] = {zero4, zero4};
            f32x4 acc2[2] = {zero4, zero4};
            bf16x8 eb0 = *(const bf16x8*)&E_frag[((ntj*2 + 0)*64 + l)*8];
            bf16x8 eb1 = *(const bf16x8*)&E_frag[((ntj*2 + 1)*64 + l)*8];
#pragma unroll
            for (int mtn = 0; mtn < 2; ++mtn) {
                acc1[mtn] = __builtin_amdgcn_mfma_f32_16x16x32_bf16(wa1[mtn][0], eb0, acc1[mtn], 0, 0, 0);
                acc2[mtn] = __builtin_amdgcn_mfma_f32_16x16x32_bf16(wa2[mtn][0], eb0, acc2[mtn], 0, 0, 0);
                acc1[mtn] = __builtin_amdgcn_mfma_f32_16x16x32_bf16(wa1[mtn][1], eb1, acc1[mtn], 0, 0, 0);
                acc2[mtn] = __builtin_amdgcn_mfma_f32_16x16x32_bf16(wa2[mtn][1], eb1, acc2[mtn], 0, 0, 0);
            }
            // lane owns edge j = ntj*16 + c, ncols colbase..+3 and colbase+16..+19
            int j = ntj*16 + c;
            const bf16* Kp = Krow0 + (long)(j0 + j)*DX;
            bf16x4 kv0 = *(const bf16x4*)&Kp[0];
            bf16x4 kv1 = *(const bf16x4*)&Kp[16];
            float sc = 0.f;
            bf16x4 y0, y1;
#pragma unroll
            for (int reg = 0; reg < 4; ++reg) {
                float kva = (float)kv0[reg];
                float kvb = (float)kv1[reg];
                float ya = qs[0][reg]*kva*(acc1[0][reg] + b1[0][reg]) + acc2[0][reg] + b2[0][reg];
                float yb = qs[1][reg]*kvb*(acc1[1][reg] + b1[1][reg]) + acc2[1][reg] + b2[1][reg];
                sc += ya + yb;
                y0[reg] = (bf16)ya;
                y1[reg] = (bf16)yb;
            }
            *(bf16x4*)(Yb + YS(j, (colbase<<1)))      = y0;
            *(bf16x4*)(Yb + YS(j, (colbase<<1) + 32)) = y1;
            sc += __shfl_xor(sc, 16);
            sc += __shfl_xor(sc, 32);
            if (g == 0) scores[srow0 + j0 + j] = sc;
        }
        __syncthreads();   // Y_s ready

        // ---- GEMM3: newE = Y @ eoutW + eoutb ----
        f32x4 acc3[2];
        acc3[0] = zero4; acc3[1] = zero4;
#pragma unroll
        for (int ks = 0; ks < 8; ++ks) {
            bf16x8 a = *(const bf16x8*)(Yb + YS(mt3*16 + c, ks*64 + g*16));
#pragma unroll
            for (int nn = 0; nn < 2; ++nn) {
                bf16x8 bw = *(const bf16x8*)&W3[(((n0_+nn)*8 + ks)*64 + l)*8];
                acc3[nn] = __builtin_amdgcn_mfma_f32_16x16x32_bf16(a, bw, acc3[nn], 0, 0, 0);
            }
        }
        long eb_ = ebase + j0;
#pragma unroll
        for (int nn = 0; nn < 2; ++nn) {
            int o = (n0_+nn)*16 + c;
            float bias = eoutb[o];
#pragma unroll
            for (int reg = 0; reg < 4; ++reg)
                newE[(eb_ + mt3*16 + g*4 + reg)*DE + o] = acc3[nn][reg] + bias;
        }
    }
}

// ================= K3: post kernel =================
// blocks [0,384): attn (2 rows/block); blocks [384,388): ypath
__global__ __launch_bounds__(256) void post_kernel(
    const float* __restrict__ scores, const float* __restrict__ V,
    const float* __restrict__ yx1, const float* __restrict__ yx2,
    const float* __restrict__ xoutW, const float* __restrict__ xoutb,
    const float* __restrict__ epart, const float* __restrict__ zx,
    const float* __restrict__ y,
    const float* __restrict__ xyW, const float* __restrict__ xyb,
    const float* __restrict__ eyW, const float* __restrict__ eyb,
    const float* __restrict__ y1W, const float* __restrict__ y1b,
    const float* __restrict__ y2W, const float* __restrict__ y2b,
    float* __restrict__ newX, float* __restrict__ outy)
{
    __shared__ __align__(16) char smemP[15360];
    int t = threadIdx.x;
    int blk = blockIdx.x;

    if (blk < 384) {
        float* s2 = (float*)smemP;            // [2][8][200]
        float* t2 = s2 + 3200;                // [2][256]
        int b = blk / 96;
        int i0 = (blk % 96) * 2;

        for (int idx = t; idx < 2*NH*NN_; idx += 256) {
            int rr = idx / (NH*NN_);
            int rem = idx - rr*(NH*NN_);
            int h = rem / NN_, j = rem - h*NN_;
            s2[(rr*NH + h)*200 + j] = scores[(((long)(b*NH + h))*NN_ + (i0+rr))*NN_ + j];
        }
        __syncthreads();
        {
            int w = t >> 6, l64 = t & 63;
            int rr = w >> 1;
#pragma unroll
            for (int hh = 0; hh < 4; ++hh) {
                int h = (w & 1)*4 + hh;
                float* srw = &s2[(rr*NH + h)*200];
                float v0 = srw[l64], v1 = srw[l64+64], v2 = srw[l64+128];
                float m = fmaxf(fmaxf(v0, v1), v2);
                m = fmaxf(m, __shfl_xor(m, 1));  m = fmaxf(m, __shfl_xor(m, 2));
                m = fmaxf(m, __shfl_xor(m, 4));  m = fmaxf(m, __shfl_xor(m, 8));
                m = fmaxf(m, __shfl_xor(m, 16)); m = fmaxf(m, __shfl_xor(m, 32));
                v0 = __expf(v0 - m); v1 = __expf(v1 - m); v2 = __expf(v2 - m);
                float sum = v0 + v1 + v2;
                sum += __shfl_xor(sum, 1);  sum += __shfl_xor(sum, 2);
                sum += __shfl_xor(sum, 4);  sum += __shfl_xor(sum, 8);
                sum += __shfl_xor(sum, 16); sum += __shfl_xor(sum, 32);
                float inv = 1.0f / sum;
                srw[l64] = v0*inv; srw[l64+64] = v1*inv; srw[l64+128] = v2*inv;
            }
        }
        __syncthreads();

        float a0 = 0.f, a1 = 0.f;
        int hd = t >> 5;
        const float* s0r = &s2[(0*NH + hd)*200];
        const float* s1r = &s2[(1*NH + hd)*200];
        const float* Vb = V + (long)b*NN_*DX + t;
        for (int j = 0; j < NN_; j += 4) {
            float vv0 = Vb[(long)(j+0)*DX];
            float vv1 = Vb[(long)(j+1)*DX];
            float vv2 = Vb[(long)(j+2)*DX];
            float vv3 = Vb[(long)(j+3)*DX];
            a0 += s0r[j]*vv0 + s0r[j+1]*vv1 + s0r[j+2]*vv2 + s0r[j+3]*vv3;
            a1 += s1r[j]*vv0 + s1r[j+1]*vv1 + s1r[j+2]*vv2 + s1r[j+3]*vv3;
        }
        float y1v = yx1[b*DX + t], y2v = yx2[b*DX + t] + 1.0f;
        t2[t] = y1v + y2v * a0;
        t2[256 + t] = y1v + y2v * a1;
        __syncthreads();

        float ax0 = xoutb[t], ax1 = ax0;
        for (int k = 0; k < DX; k += 4) {
            float w0 = xoutW[(k+0)*DX+t], w1 = xoutW[(k+1)*DX+t];
            float w2 = xoutW[(k+2)*DX+t], w3 = xoutW[(k+3)*DX+t];
            float4 x0 = *(const float4*)&t2[k];
            float4 x1 = *(const float4*)&t2[256 + k];
            ax0 += x0.x*w0 + x0.y*w1 + x0.z*w2 + x0.w*w3;
            ax1 += x1.x*w0 + x1.y*w1 + x1.z*w2 + x1.w*w3;
        }
        newX[((long)(b*NN_ + i0    ))*DX + t] = ax0;
        newX[((long)(b*NN_ + i0 + 1))*DX + t] = ax1;
    } else {
        float* pe   = (float*)smemP;    // [4][4][64]
        float* ze_s = pe + 1024;        // 256
        float* zx_s = ze_s + 256;       // 1024
        float* redx = zx_s + 1024;      // [4][64]
        float* rede = redx + 256;       // 256
        float* v_s  = rede + 256;       // 64
        float* h_s  = v_s + 64;         // 64
        int b = blk - 384;
        int o = t & 63, q = t >> 6;

        {
            float sm = 0.f, sq = 0.f, mn = 1e30f, mx = -1e30f;
            const float* ep = epart + (long)b*EBLK*256;
            for (int bb = q; bb < EBLK; bb += 4) {
                sm += ep[bb*256 + o];
                sq += ep[bb*256 + 64 + o];
                mn = fminf(mn, ep[bb*256 + 128 + o]);
                mx = fmaxf(mx, ep[bb*256 + 192 + o]);
            }
            pe[(0*4 + q)*64 + o] = sm; pe[(1*4 + q)*64 + o] = sq;
            pe[(2*4 + q)*64 + o] = mn; pe[(3*4 + q)*64 + o] = mx;
        }
        for (int cidx = t; cidx < 1024; cidx += 256) zx_s[cidx] = zx[b*1024 + cidx];
        __syncthreads();
        if (t < 64) {
            float s  = pe[t] + pe[64+t] + pe[128+t] + pe[192+t];
            float qq = pe[256+t] + pe[320+t] + pe[384+t] + pe[448+t];
            float a  = fminf(fminf(pe[512+t], pe[576+t]), fminf(pe[640+t], pe[704+t]));
            float z  = fmaxf(fmaxf(pe[768+t], pe[832+t]), fmaxf(pe[896+t], pe[960+t]));
            float cnt = (float)NSQ;
            float mean = s / cnt;
            float sd = sqrtf(fmaxf(0.f, (qq - s*s/cnt) / (cnt - 1.f)));
            ze_s[t] = mean; ze_s[64+t] = a; ze_s[128+t] = z; ze_s[192+t] = sd;
        }
        __syncthreads();

        float xa = 0.f;
        for (int k = q*256; k < q*256 + 256; ++k) xa += zx_s[k] * xyW[k*DY + o];
        float ea = 0.f;
        for (int k = q*64; k < q*64 + 64; ++k) ea += ze_s[k] * eyW[k*DY + o];
        redx[q*64 + o] = xa; rede[q*64 + o] = ea;
        __syncthreads();
        if (t < 64) {
            float a = xyb[t] + redx[t] + redx[64+t] + redx[128+t] + redx[192+t];
            float e = eyb[t] + rede[t] + rede[64+t] + rede[128+t] + rede[192+t];
            v_s[t] = y[b*DY + t] + a + e;
        }
        __syncthreads();

        float hv = 0.f;
        for (int k = q*16; k < q*16 + 16; ++k) hv += v_s[k] * y1W[k*DY + o];
        redx[q*64 + o] = hv;
        __syncthreads();
        if (t < 64)
            h_s[t] = fmaxf(y1b[t] + redx[t] + redx[64+t] + redx[128+t] + redx[192+t], 0.f);
        __syncthreads();

        float ov = 0.f;
        for (int k = q*16; k < q*16 + 16; ++k) ov += h_s[k] * y2W[k*DY + o];
        redx[q*64 + o] = ov;
        __syncthreads();
        if (t < 64)
            outy[b*DY + t] = y2b[t] + redx[t] + redx[64+t] + redx[128+t] + redx[192+t];
    }
}

// ---------------- launch ----------------
extern "C" void kernel_launch(void* const* d_in, const int* in_sizes, int n_in,
                              void* d_out, int out_size, void* d_ws, size_t ws_size,
                              hipStream_t stream) {
    const float* X     = (const float*)d_in[0];
    const float* E     = (const float*)d_in[1];
    const float* y     = (const float*)d_in[2];
    const float* qW    = (const float*)d_in[4];
    const float* qb    = (const float*)d_in[5];
    const float* kW    = (const float*)d_in[6];
    const float* kb    = (const float*)d_in[7];
    const float* vW    = (const float*)d_in[8];
    const float* vb    = (const float*)d_in[9];
    const float* emulW = (const float*)d_in[10];
    const float* emulb = (const float*)d_in[11];
    const float* eaddW = (const float*)d_in[12];
    const float* eaddb = (const float*)d_in[13];
    const float* yxmW  = (const float*)d_in[14];
    const float* yxmb  = (const float*)d_in[15];
    const float* yxaW  = (const float*)d_in[16];
    const float* yxab  = (const float*)d_in[17];
    const float* xoutW = (const float*)d_in[18];
    const float* xoutb = (const float*)d_in[19];
    const float* eoutW = (const float*)d_in[20];
    const float* eoutb = (const float*)d_in[21];
    const float* xyW   = (const float*)d_in[22];
    const float* xyb   = (const float*)d_in[23];
    const float* eyW   = (const float*)d_in[24];
    const float* eyb   = (const float*)d_in[25];
    const float* y1W   = (const float*)d_in[26];
    const float* y1b   = (const float*)d_in[27];
    const float* y2W   = (const float*)d_in[28];
    const float* y2b   = (const float*)d_in[29];

    float* out  = (float*)d_out;
    float* newX = out;
    float* newE = out + (long)ROWS*DX;
    float* outy = out + (long)ROWS*DX + (long)BSZ*NSQ*DE;

    float* ws   = (float*)d_ws;
    float* Q    = ws;                          // 196608 f
    float* V    = Q + (long)ROWS*DX;           // 196608 f
    float* yx1  = V + (long)ROWS*DX;           // 1024 f
    float* yx2  = yx1 + BSZ*DX;                // 1024 f
    float* scr  = yx2 + BSZ*DX;                // 1179648 f  [b][h][i][j]
    float* ep   = scr + (long)BSZ*NH*NSQ;      // 73728 f
    float* zx   = ep + (long)BSZ*EBLK*256;     // 4096 f
    bf16*  Kbf  = (bf16*)(zx + BSZ*4*DX);      // 196608 bf16
    bf16*  W1a  = Kbf + (long)ROWS*DX;         // 16384 bf16
    bf16*  W2a  = W1a + 16384;                 // 16384 bf16
    bf16*  W3   = W2a + 16384;                 // 16384 bf16

    front_kernel<<<629, 256, 0, stream>>>(X, E, y, qW, qb, kW, kb, vW, vb,
                                          emulW, eaddW, eoutW,
                                          yxaW, yxab, yxmW, yxmb,
                                          Q, Kbf, V, yx1, yx2, ep, zx, W1a, W2a, W3);
    edge_kernel<<<BSZ*NN_, 512, 0, stream>>>(E, Q, Kbf, W1a, W2a, W3,
                                             emulb, eaddb, eoutb, newE, scr);
    post_kernel<<<388, 256, 0, stream>>>(scr, V, yx1, yx2, xoutW, xoutb,
                                         ep, zx, y, xyW, xyb, eyW, eyb,
                                         y1W, y1b, y2W, y2b, newX, outy);
}